// Round 1
// baseline (655.436 us; speedup 1.0000x reference)
//
#include <hip/hip_runtime.h>

#define NB   4
#define H_IN 14
#define W_IN 14
#define FIN  32
#define DI   8
#define F    32
#define C    288   // 3*3*32
#define DO   16
#define HO   12
#define WO   12
#define NPOS (NB*HO*WO)   // 576
#define EPS  1e-7f

__device__ __forceinline__ float dot8(const float4* __restrict__ w,
                                      const float4 p0, const float4 p1) {
    float4 a = w[0], b = w[1];
    return a.x*p0.x + a.y*p0.y + a.z*p0.z + a.w*p0.w
         + b.x*p1.x + b.y*p1.y + b.z*p1.z + b.w*p1.w;
}

__global__ __launch_bounds__(256) void capsule_kernel(
    const float* __restrict__ x, const float* __restrict__ Wt,
    float* __restrict__ out)
{
    __shared__ float patch[C*DI];   // 9216 B   patch[c][i]
    __shared__ float cent[F*DO];    // 2048 B   centroids (iter1 then iter2)
    __shared__ float out1[F*DO];    // 2048 B   squashed iter-1 outputs
    __shared__ float agr[F*C];      // 36864 B  agreement -> cc (in place)
    __shared__ float scale_s[F];

    const int tid = threadIdx.x;
    const int pos = blockIdx.x;
    const int b   = pos / (HO*WO);
    const int rem = pos % (HO*WO);
    const int ho  = rem / WO;
    const int wo  = rem % WO;

    // ---- phase 1: load patch [288][8]; each (kh,kw) slab = 256 contiguous floats
    #pragma unroll
    for (int slab = 0; slab < 9; ++slab) {
        const int kh = slab / 3, kw = slab % 3;
        const float* src = x + (((b*H_IN + ho + kh)*W_IN + (wo + kw))*FIN)*DI;
        patch[slab*256 + tid] = src[tid];
    }
    __syncthreads();

    const float4* pv = (const float4*)patch;

    // ---- phase 2: centroids1[f,o] = (1/32) * sum_{c,i} W[f,c,o,i]*patch[c,i]
    {
        const int fo0 = tid, fo1 = tid + 256;
        const int f0 = fo0 >> 4, o0 = fo0 & 15;
        const int f1 = fo1 >> 4, o1 = fo1 & 15;
        float acc0 = 0.f, acc1 = 0.f;
        for (int c = 0; c < C; ++c) {
            const float4 p0 = pv[c*2], p1 = pv[c*2+1];
            const float4* w0 = (const float4*)(Wt + ((f0*C + c)*DO + o0)*DI);
            const float4* w1 = (const float4*)(Wt + ((f1*C + c)*DO + o1)*DI);
            acc0 += dot8(w0, p0, p1);
            acc1 += dot8(w1, p0, p1);
        }
        cent[fo0] = acc0 * (1.f/32.f);
        cent[fo1] = acc1 * (1.f/32.f);
    }
    __syncthreads();

    // ---- phase 3: out1 = squash(centroids1) along o
    if (tid < F) {
        float sn = 0.f;
        #pragma unroll
        for (int o = 0; o < DO; ++o) { float v = cent[tid*DO + o]; sn += v*v; }
        const float sc = (sn/(1.f + sn)) * rsqrtf(sn + EPS);
        #pragma unroll
        for (int o = 0; o < DO; ++o) out1[tid*DO + o] = cent[tid*DO + o] * sc;
    }
    __syncthreads();

    // ---- phase 4: agreement[f,c] = sum_o out1[f,o] * (sum_i W[f,c,o,i]*patch[c,i])
    #pragma unroll 1
    for (int r = 0; r < (F*C)/256; ++r) {           // 36 rounds
        const int p = tid + 256*r;
        const int f = p / C, c = p % C;
        const float4* wrow = (const float4*)(Wt + (f*C + c)*DO*DI);
        const float4 p0 = pv[c*2], p1 = pv[c*2+1];
        float a = 0.f;
        #pragma unroll
        for (int o = 0; o < DO; ++o) {
            a += dot8(wrow + o*2, p0, p1) * out1[f*DO + o];
        }
        agr[p] = a;
    }
    __syncthreads();

    // ---- phase 5: cc = softmax over f (axis 3 of [B,Ho,Wo,F,C]) per c
    for (int c = tid; c < C; c += 256) {
        float m = -1e30f;
        #pragma unroll
        for (int f = 0; f < F; ++f) m = fmaxf(m, agr[f*C + c]);
        float s = 0.f;
        #pragma unroll
        for (int f = 0; f < F; ++f) {
            const float e = __expf(agr[f*C + c] - m);
            agr[f*C + c] = e;
            s += e;
        }
        const float inv = 1.f / s;
        #pragma unroll
        for (int f = 0; f < F; ++f) agr[f*C + c] *= inv;
    }
    __syncthreads();

    // ---- phase 6: centroids2[f,o] = sum_c cc[f,c] * (sum_i W[f,c,o,i]*patch[c,i])
    {
        const int fo0 = tid, fo1 = tid + 256;
        const int f0 = fo0 >> 4, o0 = fo0 & 15;
        const int f1 = fo1 >> 4, o1 = fo1 & 15;
        float acc0 = 0.f, acc1 = 0.f;
        for (int c = 0; c < C; ++c) {
            const float4 p0 = pv[c*2], p1 = pv[c*2+1];
            const float4* w0 = (const float4*)(Wt + ((f0*C + c)*DO + o0)*DI);
            const float4* w1 = (const float4*)(Wt + ((f1*C + c)*DO + o1)*DI);
            acc0 += agr[f0*C + c] * dot8(w0, p0, p1);
            acc1 += agr[f1*C + c] * dot8(w1, p0, p1);
        }
        cent[fo0] = acc0;
        cent[fo1] = acc1;
    }
    __syncthreads();

    // ---- phase 7: squash + store
    if (tid < F) {
        float sn = 0.f;
        #pragma unroll
        for (int o = 0; o < DO; ++o) { float v = cent[tid*DO + o]; sn += v*v; }
        scale_s[tid] = (sn/(1.f + sn)) * rsqrtf(sn + EPS);
    }
    __syncthreads();

    out[pos*(F*DO) + tid]       = cent[tid]       * scale_s[tid >> 4];
    out[pos*(F*DO) + tid + 256] = cent[tid + 256] * scale_s[(tid >> 4) + 16];
}

extern "C" void kernel_launch(void* const* d_in, const int* in_sizes, int n_in,
                              void* d_out, int out_size, void* d_ws, size_t ws_size,
                              hipStream_t stream) {
    const float* x  = (const float*)d_in[0];
    const float* Wt = (const float*)d_in[1];
    float* out = (float*)d_out;
    capsule_kernel<<<NPOS, 256, 0, stream>>>(x, Wt, out);
}

// Round 2
// 356.076 us; speedup vs baseline: 1.8407x; 1.8407x over previous
//
#include <hip/hip_runtime.h>

#define NB   4
#define H_IN 14
#define W_IN 14
#define FIN  32
#define DI   8
#define F    32
#define C    288   // 3*3*32
#define DO   16
#define HO   12
#define WO   12
#define NPOS (NB*HO*WO)   // 576
#define WELEMS (F*C*DO*DI) // 1,179,648
#define EPS  1e-7f

// ---------------- W fp32 -> bf16 conversion (runs every launch; ws is re-poisoned) ----
__device__ __forceinline__ unsigned short f2bf_rne(float f) {
    unsigned int u = __float_as_uint(f);
    unsigned int r = (u + 0x7fffu + ((u >> 16) & 1u)) >> 16;
    return (unsigned short)r;
}

__global__ __launch_bounds__(256) void convW_kernel(const float* __restrict__ Wf,
                                                    unsigned short* __restrict__ Wb) {
    const int i = blockIdx.x * 256 + threadIdx.x;     // one float4 -> 4 bf16 per thread
    float4 v = ((const float4*)Wf)[i];
    ushort4 o;
    o.x = f2bf_rne(v.x); o.y = f2bf_rne(v.y); o.z = f2bf_rne(v.z); o.w = f2bf_rne(v.w);
    ((ushort4*)Wb)[i] = o;
}

// 8 bf16 (one uint4) dotted with 8 fp32 from LDS, fp32 accumulate (unpack is exact)
__device__ __forceinline__ float dot8bf(const uint4 w, const float4 p0, const float4 p1) {
    float s;
    s  = __uint_as_float(w.x << 16)          * p0.x;
    s += __uint_as_float(w.x & 0xffff0000u)  * p0.y;
    s += __uint_as_float(w.y << 16)          * p0.z;
    s += __uint_as_float(w.y & 0xffff0000u)  * p0.w;
    s += __uint_as_float(w.z << 16)          * p1.x;
    s += __uint_as_float(w.z & 0xffff0000u)  * p1.y;
    s += __uint_as_float(w.w << 16)          * p1.z;
    s += __uint_as_float(w.w & 0xffff0000u)  * p1.w;
    return s;
}

__global__ __launch_bounds__(256) void capsule_kernel_bf16w(
    const float* __restrict__ x, const unsigned short* __restrict__ Wb,
    float* __restrict__ out)
{
    __shared__ float patch[C*DI];   // 9216 B   patch[c][i]
    __shared__ float cent[F*DO];    // 2048 B
    __shared__ float out1[F*DO];    // 2048 B
    __shared__ float agr[F*C];      // 36864 B
    __shared__ float scale_s[F];

    const int tid = threadIdx.x;
    const int pos = blockIdx.x;
    const int b   = pos / (HO*WO);
    const int rem = pos % (HO*WO);
    const int ho  = rem / WO;
    const int wo  = rem % WO;

    // ---- phase 1: load patch [288][8]
    #pragma unroll
    for (int slab = 0; slab < 9; ++slab) {
        const int kh = slab / 3, kw = slab % 3;
        const float* src = x + (((b*H_IN + ho + kh)*W_IN + (wo + kw))*FIN)*DI;
        patch[slab*256 + tid] = src[tid];
    }
    __syncthreads();

    const float4* pv = (const float4*)patch;

    // ---- phase 2: centroids1[f,o] = (1/32) * sum_{c,i} W[f,c,o,i]*patch[c,i]
    {
        const int fo0 = tid, fo1 = tid + 256;
        const int f0 = fo0 >> 4, o0 = fo0 & 15;
        const int f1 = fo1 >> 4, o1 = fo1 & 15;
        const uint4* w0base = (const uint4*)(Wb + (f0*C*DO + o0)*DI);
        const uint4* w1base = (const uint4*)(Wb + (f1*C*DO + o1)*DI);
        float acc0 = 0.f, acc1 = 0.f;
        #pragma unroll 4
        for (int c = 0; c < C; ++c) {
            const float4 p0 = pv[c*2], p1 = pv[c*2+1];
            acc0 += dot8bf(w0base[c*DO], p0, p1);
            acc1 += dot8bf(w1base[c*DO], p0, p1);
        }
        cent[fo0] = acc0 * (1.f/32.f);
        cent[fo1] = acc1 * (1.f/32.f);
    }
    __syncthreads();

    // ---- phase 3: out1 = squash(centroids1)
    if (tid < F) {
        float sn = 0.f;
        #pragma unroll
        for (int o = 0; o < DO; ++o) { float v = cent[tid*DO + o]; sn += v*v; }
        const float sc = (sn/(1.f + sn)) * rsqrtf(sn + EPS);
        #pragma unroll
        for (int o = 0; o < DO; ++o) out1[tid*DO + o] = cent[tid*DO + o] * sc;
    }
    __syncthreads();

    // ---- phase 4: agreement[f,c] = sum_o pred[f,c,o] * out1[f,o]
    #pragma unroll 1
    for (int r = 0; r < (F*C)/256; ++r) {           // 36 rounds
        const int p = tid + 256*r;
        const int f = p / C, c = p % C;
        const uint4* wrow = (const uint4*)(Wb + (f*C + c)*DO*DI);
        const float4 p0 = pv[c*2], p1 = pv[c*2+1];
        float a = 0.f;
        #pragma unroll
        for (int o = 0; o < DO; ++o) {
            a += dot8bf(wrow[o], p0, p1) * out1[f*DO + o];
        }
        agr[p] = a;
    }
    __syncthreads();

    // ---- phase 5: softmax over f per c
    for (int c = tid; c < C; c += 256) {
        float m = -1e30f;
        #pragma unroll
        for (int f = 0; f < F; ++f) m = fmaxf(m, agr[f*C + c]);
        float s = 0.f;
        #pragma unroll
        for (int f = 0; f < F; ++f) {
            const float e = __expf(agr[f*C + c] - m);
            agr[f*C + c] = e;
            s += e;
        }
        const float inv = 1.f / s;
        #pragma unroll
        for (int f = 0; f < F; ++f) agr[f*C + c] *= inv;
    }
    __syncthreads();

    // ---- phase 6: centroids2[f,o] = sum_c cc[f,c] * pred[f,c,o]
    {
        const int fo0 = tid, fo1 = tid + 256;
        const int f0 = fo0 >> 4, o0 = fo0 & 15;
        const int f1 = fo1 >> 4, o1 = fo1 & 15;
        const uint4* w0base = (const uint4*)(Wb + (f0*C*DO + o0)*DI);
        const uint4* w1base = (const uint4*)(Wb + (f1*C*DO + o1)*DI);
        float acc0 = 0.f, acc1 = 0.f;
        #pragma unroll 4
        for (int c = 0; c < C; ++c) {
            const float4 p0 = pv[c*2], p1 = pv[c*2+1];
            acc0 += agr[f0*C + c] * dot8bf(w0base[c*DO], p0, p1);
            acc1 += agr[f1*C + c] * dot8bf(w1base[c*DO], p0, p1);
        }
        cent[fo0] = acc0;
        cent[fo1] = acc1;
    }
    __syncthreads();

    // ---- phase 7: squash + store
    if (tid < F) {
        float sn = 0.f;
        #pragma unroll
        for (int o = 0; o < DO; ++o) { float v = cent[tid*DO + o]; sn += v*v; }
        scale_s[tid] = (sn/(1.f + sn)) * rsqrtf(sn + EPS);
    }
    __syncthreads();

    out[pos*(F*DO) + tid]       = cent[tid]       * scale_s[tid >> 4];
    out[pos*(F*DO) + tid + 256] = cent[tid + 256] * scale_s[(tid >> 4) + 16];
}

// -------- fp32 fallback (only if ws is too small for bf16 W) ------------------------
__device__ __forceinline__ float dot8(const float4* __restrict__ w,
                                      const float4 p0, const float4 p1) {
    float4 a = w[0], b = w[1];
    return a.x*p0.x + a.y*p0.y + a.z*p0.z + a.w*p0.w
         + b.x*p1.x + b.y*p1.y + b.z*p1.z + b.w*p1.w;
}

__global__ __launch_bounds__(256) void capsule_kernel_f32(
    const float* __restrict__ x, const float* __restrict__ Wt,
    float* __restrict__ out)
{
    __shared__ float patch[C*DI];
    __shared__ float cent[F*DO];
    __shared__ float out1[F*DO];
    __shared__ float agr[F*C];
    __shared__ float scale_s[F];

    const int tid = threadIdx.x;
    const int pos = blockIdx.x;
    const int b   = pos / (HO*WO);
    const int rem = pos % (HO*WO);
    const int ho  = rem / WO;
    const int wo  = rem % WO;

    #pragma unroll
    for (int slab = 0; slab < 9; ++slab) {
        const int kh = slab / 3, kw = slab % 3;
        const float* src = x + (((b*H_IN + ho + kh)*W_IN + (wo + kw))*FIN)*DI;
        patch[slab*256 + tid] = src[tid];
    }
    __syncthreads();

    const float4* pv = (const float4*)patch;

    {
        const int fo0 = tid, fo1 = tid + 256;
        const int f0 = fo0 >> 4, o0 = fo0 & 15;
        const int f1 = fo1 >> 4, o1 = fo1 & 15;
        float acc0 = 0.f, acc1 = 0.f;
        for (int c = 0; c < C; ++c) {
            const float4 p0 = pv[c*2], p1 = pv[c*2+1];
            acc0 += dot8((const float4*)(Wt + ((f0*C + c)*DO + o0)*DI), p0, p1);
            acc1 += dot8((const float4*)(Wt + ((f1*C + c)*DO + o1)*DI), p0, p1);
        }
        cent[fo0] = acc0 * (1.f/32.f);
        cent[fo1] = acc1 * (1.f/32.f);
    }
    __syncthreads();

    if (tid < F) {
        float sn = 0.f;
        #pragma unroll
        for (int o = 0; o < DO; ++o) { float v = cent[tid*DO + o]; sn += v*v; }
        const float sc = (sn/(1.f + sn)) * rsqrtf(sn + EPS);
        #pragma unroll
        for (int o = 0; o < DO; ++o) out1[tid*DO + o] = cent[tid*DO + o] * sc;
    }
    __syncthreads();

    #pragma unroll 1
    for (int r = 0; r < (F*C)/256; ++r) {
        const int p = tid + 256*r;
        const int f = p / C, c = p % C;
        const float4* wrow = (const float4*)(Wt + (f*C + c)*DO*DI);
        const float4 p0 = pv[c*2], p1 = pv[c*2+1];
        float a = 0.f;
        #pragma unroll
        for (int o = 0; o < DO; ++o) a += dot8(wrow + o*2, p0, p1) * out1[f*DO + o];
        agr[p] = a;
    }
    __syncthreads();

    for (int c = tid; c < C; c += 256) {
        float m = -1e30f;
        #pragma unroll
        for (int f = 0; f < F; ++f) m = fmaxf(m, agr[f*C + c]);
        float s = 0.f;
        #pragma unroll
        for (int f = 0; f < F; ++f) {
            const float e = __expf(agr[f*C + c] - m);
            agr[f*C + c] = e; s += e;
        }
        const float inv = 1.f / s;
        #pragma unroll
        for (int f = 0; f < F; ++f) agr[f*C + c] *= inv;
    }
    __syncthreads();

    {
        const int fo0 = tid, fo1 = tid + 256;
        const int f0 = fo0 >> 4, o0 = fo0 & 15;
        const int f1 = fo1 >> 4, o1 = fo1 & 15;
        float acc0 = 0.f, acc1 = 0.f;
        for (int c = 0; c < C; ++c) {
            const float4 p0 = pv[c*2], p1 = pv[c*2+1];
            acc0 += agr[f0*C + c] * dot8((const float4*)(Wt + ((f0*C + c)*DO + o0)*DI), p0, p1);
            acc1 += agr[f1*C + c] * dot8((const float4*)(Wt + ((f1*C + c)*DO + o1)*DI), p0, p1);
        }
        cent[fo0] = acc0;
        cent[fo1] = acc1;
    }
    __syncthreads();

    if (tid < F) {
        float sn = 0.f;
        #pragma unroll
        for (int o = 0; o < DO; ++o) { float v = cent[tid*DO + o]; sn += v*v; }
        scale_s[tid] = (sn/(1.f + sn)) * rsqrtf(sn + EPS);
    }
    __syncthreads();

    out[pos*(F*DO) + tid]       = cent[tid]       * scale_s[tid >> 4];
    out[pos*(F*DO) + tid + 256] = cent[tid + 256] * scale_s[(tid >> 4) + 16];
}

extern "C" void kernel_launch(void* const* d_in, const int* in_sizes, int n_in,
                              void* d_out, int out_size, void* d_ws, size_t ws_size,
                              hipStream_t stream) {
    const float* x  = (const float*)d_in[0];
    const float* Wt = (const float*)d_in[1];
    float* out = (float*)d_out;

    if (ws_size >= (size_t)WELEMS * sizeof(unsigned short)) {
        unsigned short* Wb = (unsigned short*)d_ws;
        convW_kernel<<<WELEMS/4/256, 256, 0, stream>>>(Wt, Wb);   // 1152 blocks
        capsule_kernel_bf16w<<<NPOS, 256, 0, stream>>>(x, Wb, out);
    } else {
        capsule_kernel_f32<<<NPOS, 256, 0, stream>>>(x, Wt, out);
    }
}